// Round 1
// baseline (577.679 us; speedup 1.0000x reference)
//
#include <hip/hip_runtime.h>
#include <stdint.h>

#define LN_EPS 1e-5f

// ---------- bf16 helpers (RNE, bit-level; no dependence on __hip_bfloat16 layout) ----------
static __device__ __forceinline__ unsigned short f2bf_bits(float f) {
  union { float f; unsigned u; } v; v.f = f;
  unsigned r = v.u + 0x7FFFu + ((v.u >> 16) & 1u);
  return (unsigned short)(r >> 16);
}
static __device__ __forceinline__ float bf2f(unsigned short h) {
  union { unsigned u; float f; } v; v.u = ((unsigned)h) << 16;
  return v.f;
}

typedef __bf16 bf16x8 __attribute__((ext_vector_type(8)));
typedef float floatx4 __attribute__((ext_vector_type(4)));

// ---------- async global->LDS, 16B per lane (global_load_lds_dwordx4) ----------
typedef __attribute__((address_space(1))) unsigned int* gas_ptr;
typedef __attribute__((address_space(3))) unsigned int* las_ptr;
static __device__ __forceinline__ void async_cp16(const void* g, void* l) {
  __builtin_amdgcn_global_load_lds((gas_ptr)g, (las_ptr)l, 16, 0, 0);
}

// =====================================================================================
// K_a: fp32 -> bf16 weight conversion: w2 [256x128], w3 right half [512x256], w4 [1024x512]
// =====================================================================================
__global__ __launch_bounds__(256) void wconv_kernel(
    const float* __restrict__ w2, const float* __restrict__ w3,
    const float* __restrict__ w4, unsigned short* __restrict__ w2b,
    unsigned short* __restrict__ w3Rb, unsigned short* __restrict__ w4b) {
  int idx = blockIdx.x * 256 + threadIdx.x;   // 688128 total
  if (idx < 32768) {
    w2b[idx] = f2bf_bits(w2[idx]);
  } else if (idx < 32768 + 131072) {
    int t = idx - 32768;
    int p = t >> 8, k = t & 255;
    w3Rb[t] = f2bf_bits(w3[p * 512 + 256 + k]);   // w3[:, 256:512]
  } else {
    int t = idx - 163840;
    w4b[t] = f2bf_bits(w4[t]);
  }
}

// =====================================================================================
// K_b: conv1 (K=3, fp32 exact) + LayerNorm(128) + mask + relu -> h2 bf16 [131072 x 128]
// one wave per point; lane handles channels 2*lane, 2*lane+1
// =====================================================================================
__global__ __launch_bounds__(256) void conv1_ln_kernel(
    const float* __restrict__ points, const int* __restrict__ mask,
    const float* __restrict__ w1, const float* __restrict__ g1,
    const float* __restrict__ be1, unsigned short* __restrict__ h2) {
  const int lane = threadIdx.x & 63;
  const int wv = threadIdx.x >> 6;
  const size_t p = (size_t)blockIdx.x * 4 + wv;     // point index (b*4096+n)
  const float x0 = points[p * 3 + 0];
  const float x1 = points[p * 3 + 1];
  const float x2 = points[p * 3 + 2];
  const int c0 = lane * 2, c1 = c0 + 1;
  float h00 = w1[c0 * 3] * x0 + w1[c0 * 3 + 1] * x1 + w1[c0 * 3 + 2] * x2;
  float h01 = w1[c1 * 3] * x0 + w1[c1 * 3 + 1] * x1 + w1[c1 * 3 + 2] * x2;
  float s = h00 + h01;
  for (int o = 32; o; o >>= 1) s += __shfl_xor(s, o);
  const float mu = s * (1.f / 128.f);
  const float d0 = h00 - mu, d1 = h01 - mu;
  float q = d0 * d0 + d1 * d1;
  for (int o = 32; o; o >>= 1) q += __shfl_xor(q, o);
  const float rs = rsqrtf(q * (1.f / 128.f) + LN_EPS);
  const bool vis = (mask[p] != 0);
  const float y0 = vis ? fmaxf(d0 * rs * g1[c0] + be1[c0], 0.f) : 0.f;
  const float y1 = vis ? fmaxf(d1 * rs * g1[c1] + be1[c1], 0.f) : 0.f;
  union { unsigned u; unsigned short s2[2]; } pk;
  pk.s2[0] = f2bf_bits(y0);
  pk.s2[1] = f2bf_bits(y1);
  ((unsigned*)h2)[p * 64 + lane] = pk.u;
}

// =====================================================================================
// MFMA GEMM: C[M,N] = A[M,K] * Bw[N,K]^T  (bf16 in, fp32 acc), m97-style 128x128 tile.
// EPI 0: out bf16 = acc + extra[col]                       (bias)
// EPI 1: out bf16 = acc + extra[(row>>12)*N + col]         (per-batch cvec)
// EPI 2: out fp32 pmax[blockRow*N + col] = max over 128 rows of acc  (no bias)
// =====================================================================================
template <int EPI>
__global__ __launch_bounds__(256) void gemm_bt(
    const unsigned short* __restrict__ A, const unsigned short* __restrict__ Bw,
    void* __restrict__ outp, const float* __restrict__ extra,
    int M, int N, int K) {
  __shared__ __align__(16) char smA[128 * 64];   // 128 rows x 32 bf16 (64B), unpadded
  __shared__ __align__(16) char smB[128 * 64];
  __shared__ float lmax[2][128];                 // EPI2 only

  const int tid = threadIdx.x;
  const int lane = tid & 63;
  const int w = tid >> 6;          // wave 0..3
  const int wm = w >> 1, wn = w & 1;
  const size_t rowBase = (size_t)blockIdx.x * 128;
  const int colBase = blockIdx.y * 128;

  floatx4 acc[4][4];
  const floatx4 zero = {0.f, 0.f, 0.f, 0.f};
#pragma unroll
  for (int i = 0; i < 4; ++i)
#pragma unroll
    for (int j = 0; j < 4; ++j) acc[i][j] = zero;

  // staging addressing: wave w stages rows [w*32, w*32+32) of both tiles, 2 calls each
  const int rSub = lane >> 2;            // 0..15
  const int cb16 = (lane & 3) * 16;      // byte within 64B row chunk
  const size_t Kb = (size_t)K * 2;       // row stride bytes
  const char* gA = (const char*)A + (rowBase + (size_t)(w * 32 + rSub)) * Kb + cb16;
  const char* gB = (const char*)Bw + ((size_t)colBase + (size_t)(w * 32 + rSub)) * Kb + cb16;
  char* lA = smA + w * 2048;             // wave-uniform LDS base; lane data lands at +lane*16
  char* lB = smB + w * 2048;
  const size_t skip16 = 16 * Kb;

  // fragment addressing
  const int fm = lane & 15, fq = lane >> 4;
  const char* pa0 = smA + (wm * 64 + fm) * 64 + fq * 16;
  const char* pb0 = smB + (wn * 64 + fm) * 64 + fq * 16;

  for (int k0 = 0; k0 < K; k0 += 32) {
    async_cp16(gA, lA);
    async_cp16(gA + skip16, lA + 1024);
    async_cp16(gB, lB);
    async_cp16(gB + skip16, lB + 1024);
    gA += 64; gB += 64;                  // advance 32 bf16
    __syncthreads();                     // drains vmcnt for global_load_lds
    bf16x8 af[4], bg[4];
#pragma unroll
    for (int i = 0; i < 4; ++i) af[i] = *(const bf16x8*)(pa0 + i * 16 * 64);
#pragma unroll
    for (int j = 0; j < 4; ++j) bg[j] = *(const bf16x8*)(pb0 + j * 16 * 64);
#pragma unroll
    for (int i = 0; i < 4; ++i)
#pragma unroll
      for (int j = 0; j < 4; ++j)
        acc[i][j] = __builtin_amdgcn_mfma_f32_16x16x32_bf16(af[i], bg[j], acc[i][j], 0, 0, 0);
    __syncthreads();
  }

  if (EPI <= 1) {
    unsigned short* O = (unsigned short*)outp;
#pragma unroll
    for (int j = 0; j < 4; ++j) {
      const int col = colBase + wn * 64 + j * 16 + fm;
      const float ex = (EPI == 0) ? extra[col] : extra[(rowBase >> 12) * (size_t)N + col];
#pragma unroll
      for (int i = 0; i < 4; ++i) {
        const size_t row0 = rowBase + wm * 64 + i * 16 + fq * 4;
#pragma unroll
        for (int r = 0; r < 4; ++r) {
          O[(row0 + r) * (size_t)N + col] = f2bf_bits(acc[i][j][r] + ex);
        }
      }
    }
  } else {
    // column-max over this block's 128 rows
    float m4[4];
#pragma unroll
    for (int j = 0; j < 4; ++j) {
      float m = -1e30f;
#pragma unroll
      for (int i = 0; i < 4; ++i)
#pragma unroll
        for (int r = 0; r < 4; ++r) m = fmaxf(m, acc[i][j][r]);
      m = fmaxf(m, __shfl_xor(m, 16));
      m = fmaxf(m, __shfl_xor(m, 32));
      m4[j] = m;   // max over this wave's 64 rows for col wn*64 + j*16 + fm
    }
    const float sel = (fq == 0) ? m4[0] : (fq == 1) ? m4[1] : (fq == 2) ? m4[2] : m4[3];
    lmax[wm][wn * 64 + fq * 16 + fm] = sel;
    __syncthreads();
    if (tid < 128) {
      const float v = fmaxf(lmax[0][tid], lmax[1][tid]);
      ((float*)outp)[(size_t)blockIdx.x * N + colBase + tid] = v;
    }
  }
}

// =====================================================================================
// gmax partials: max over 256-row chunks of h3 [B,4096,256] -> pg [B,16,256]
// =====================================================================================
__global__ __launch_bounds__(256) void gmax_part_kernel(
    const unsigned short* __restrict__ h3, float* __restrict__ pg) {
  const int b = blockIdx.x, s = blockIdx.y, t = threadIdx.x;
  const unsigned short* base = h3 + ((size_t)(b * 4096 + s * 256)) * 256 + t;
  float m = -1e30f;
  for (int r = 0; r < 256; ++r) m = fmaxf(m, bf2f(base[(size_t)r * 256]));
  pg[((size_t)b * 16 + s) * 256 + t] = m;
}

__global__ __launch_bounds__(256) void gmax_red_kernel(
    const float* __restrict__ pg, float* __restrict__ gmax) {
  const int b = blockIdx.x, t = threadIdx.x;
  float m = -1e30f;
  for (int s = 0; s < 16; ++s) m = fmaxf(m, pg[((size_t)b * 16 + s) * 256 + t]);
  gmax[b * 256 + t] = m;
}

// =====================================================================================
// cvec[b][p] = sum_{c<256} w3[p][c] * gmax[b][c]   (fp32 exact, tiny)
// =====================================================================================
__global__ __launch_bounds__(64) void cvec_kernel(
    const float* __restrict__ w3, const float* __restrict__ gmax,
    float* __restrict__ cvec) {
  __shared__ float gm[256];
  const int b = blockIdx.x, t = threadIdx.x;
  const int p = blockIdx.y * 64 + t;
  for (int i = 0; i < 4; ++i) gm[t * 4 + i] = gmax[b * 256 + t * 4 + i];
  __syncthreads();
  const float* wr = w3 + (size_t)p * 512;
  float s = 0.f;
  for (int c = 0; c < 256; ++c) s += wr[c] * gm[c];
  cvec[b * 512 + p] = s;
}

// =====================================================================================
// K_h: LayerNorm(512) + mask + relu, in place on h46 bf16 [131072 x 512]
// one wave per point; lane handles 8 channels (16B vector load/store)
// =====================================================================================
__global__ __launch_bounds__(256) void ln2_kernel(
    unsigned short* __restrict__ h46, const int* __restrict__ mask,
    const float* __restrict__ g2, const float* __restrict__ be2) {
  const int lane = threadIdx.x & 63;
  const int wv = threadIdx.x >> 6;
  const size_t p = (size_t)blockIdx.x * 4 + wv;
  unsigned short* row = h46 + p * 512;
  const int c0 = lane * 8;
  union { uint4 v; unsigned short s[8]; } in;
  in.v = *(const uint4*)(row + c0);
  float f[8];
  float s = 0.f;
#pragma unroll
  for (int k = 0; k < 8; ++k) { f[k] = bf2f(in.s[k]); s += f[k]; }
  for (int o = 32; o; o >>= 1) s += __shfl_xor(s, o);
  const float mu = s * (1.f / 512.f);
  float q = 0.f;
#pragma unroll
  for (int k = 0; k < 8; ++k) { const float d = f[k] - mu; q += d * d; }
  for (int o = 32; o; o >>= 1) q += __shfl_xor(q, o);
  const float rs = rsqrtf(q * (1.f / 512.f) + LN_EPS);
  const bool vis = (mask[p] != 0);
  union { uint4 v; unsigned short s[8]; } outv;
#pragma unroll
  for (int k = 0; k < 8; ++k) {
    const float y = vis ? fmaxf((f[k] - mu) * rs * g2[c0 + k] + be2[c0 + k], 0.f) : 0.f;
    outv.s[k] = f2bf_bits(y);
  }
  *(uint4*)(row + c0) = outv.v;
}

// =====================================================================================
// K_j: out[b][f] = max over 32 row-blocks of pmax + b4[f]
// =====================================================================================
__global__ __launch_bounds__(256) void final_kernel(
    const float* __restrict__ pmax, const float* __restrict__ b4,
    float* __restrict__ out) {
  const int idx = blockIdx.x * 256 + threadIdx.x;
  const int b = idx >> 10, f = idx & 1023;
  float m = -1e30f;
  for (int r = 0; r < 32; ++r) m = fmaxf(m, pmax[((size_t)(b * 32 + r)) * 1024 + f]);
  out[idx] = m + b4[f];
}

// =====================================================================================
extern "C" void kernel_launch(void* const* d_in, const int* in_sizes, int n_in,
                              void* d_out, int out_size, void* d_ws, size_t ws_size,
                              hipStream_t stream) {
  const float* points = (const float*)d_in[0];
  const int* mask = (const int*)d_in[1];
  const float* w1 = (const float*)d_in[2];
  const float* g1 = (const float*)d_in[3];
  const float* be1 = (const float*)d_in[4];
  const float* w2 = (const float*)d_in[5];
  const float* b2 = (const float*)d_in[6];
  const float* w3 = (const float*)d_in[7];
  const float* g2 = (const float*)d_in[8];
  const float* be2 = (const float*)d_in[9];
  const float* w4 = (const float*)d_in[10];
  const float* b4 = (const float*)d_in[11];
  float* out = (float*)d_out;
  char* ws = (char*)d_ws;

  // workspace layout (h46 aliases h2: h2 is dead before GEMM3 writes h46)
  const size_t OFF_H46 = 0;                         // 134217728 B (bf16 131072x512)
  const size_t OFF_H2 = 0;                          //  33554432 B (bf16 131072x128)
  const size_t OFF_H3 = 134217728;                  //  67108864 B (bf16 131072x256)
  const size_t OFF_W2B = OFF_H3 + 67108864;         //     65536 B
  const size_t OFF_W3RB = OFF_W2B + 65536;          //    262144 B
  const size_t OFF_W4B = OFF_W3RB + 262144;         //   1048576 B
  const size_t OFF_PG = OFF_W4B + 1048576;          //    524288 B
  const size_t OFF_GMAX = OFF_PG + 524288;          //     32768 B
  const size_t OFF_CVEC = OFF_GMAX + 32768;         //     65536 B
  const size_t OFF_PMAX = OFF_CVEC + 65536;         //   4194304 B  (total ~198 MB)

  unsigned short* h2 = (unsigned short*)(ws + OFF_H2);
  unsigned short* h3 = (unsigned short*)(ws + OFF_H3);
  unsigned short* h46 = (unsigned short*)(ws + OFF_H46);
  unsigned short* w2b = (unsigned short*)(ws + OFF_W2B);
  unsigned short* w3Rb = (unsigned short*)(ws + OFF_W3RB);
  unsigned short* w4b = (unsigned short*)(ws + OFF_W4B);
  float* pg = (float*)(ws + OFF_PG);
  float* gmaxp = (float*)(ws + OFF_GMAX);
  float* cvecp = (float*)(ws + OFF_CVEC);
  float* pmaxp = (float*)(ws + OFF_PMAX);

  // 1. weights fp32->bf16
  wconv_kernel<<<2688, 256, 0, stream>>>(w2, w3, w4, w2b, w3Rb, w4b);
  // 2. conv1 + LN1 + mask + relu -> h2
  conv1_ln_kernel<<<32768, 256, 0, stream>>>(points, mask, w1, g1, be1, h2);
  // 3. h3 = h2 @ w2^T + b2
  gemm_bt<0><<<dim3(1024, 2), 256, 0, stream>>>(h2, w2b, (void*)h3, b2, 131072, 256, 128);
  // 4. gmax = max over N of h3
  gmax_part_kernel<<<dim3(32, 16), 256, 0, stream>>>(h3, pg);
  gmax_red_kernel<<<32, 256, 0, stream>>>(pg, gmaxp);
  // 5. cvec = w3[:, :256] @ gmax
  cvec_kernel<<<dim3(32, 8), 64, 0, stream>>>(w3, gmaxp, cvecp);
  // 6. h4 = h3 @ w3[:,256:]^T + cvec[b]
  gemm_bt<1><<<dim3(1024, 4), 256, 0, stream>>>(h3, w3Rb, (void*)h46, cvecp, 131072, 512, 256);
  // 7. LN2 + mask + relu in place
  ln2_kernel<<<32768, 256, 0, stream>>>(h46, mask, g2, be2);
  // 8. h7 = h6 @ w4^T (no bias), fused per-block column-max -> pmax
  gemm_bt<2><<<dim3(1024, 8), 256, 0, stream>>>(h46, w4b, (void*)pmaxp, nullptr, 131072, 1024, 512);
  // 9. out = max over row-blocks + b4
  final_kernel<<<128, 256, 0, stream>>>(pmaxp, b4, out);
}

// Round 2
// 531.613 us; speedup vs baseline: 1.0867x; 1.0867x over previous
//
#include <hip/hip_runtime.h>
#include <stdint.h>

#define LN_EPS 1e-5f

// ---------- bf16 helpers (RNE, bit-level) ----------
static __device__ __forceinline__ unsigned short f2bf_bits(float f) {
  union { float f; unsigned u; } v; v.f = f;
  unsigned r = v.u + 0x7FFFu + ((v.u >> 16) & 1u);
  return (unsigned short)(r >> 16);
}
static __device__ __forceinline__ float bf2f(unsigned short h) {
  union { unsigned u; float f; } v; v.u = ((unsigned)h) << 16;
  return v.f;
}

typedef __bf16 bf16x8 __attribute__((ext_vector_type(8)));
typedef float floatx4 __attribute__((ext_vector_type(4)));

// ---------- async global->LDS, 16B per lane ----------
typedef __attribute__((address_space(1))) unsigned int* gas_ptr;
typedef __attribute__((address_space(3))) unsigned int* las_ptr;
static __device__ __forceinline__ void async_cp16(const void* g, void* l) {
  __builtin_amdgcn_global_load_lds((gas_ptr)g, (las_ptr)l, 16, 0, 0);
}

// =====================================================================================
// K_a: fp32 -> bf16 weight conversion
// =====================================================================================
__global__ __launch_bounds__(256) void wconv_kernel(
    const float* __restrict__ w2, const float* __restrict__ w3,
    const float* __restrict__ w4, unsigned short* __restrict__ w2b,
    unsigned short* __restrict__ w3Rb, unsigned short* __restrict__ w4b) {
  int idx = blockIdx.x * 256 + threadIdx.x;   // 688128 total
  if (idx < 32768) {
    w2b[idx] = f2bf_bits(w2[idx]);
  } else if (idx < 32768 + 131072) {
    int t = idx - 32768;
    int p = t >> 8, k = t & 255;
    w3Rb[t] = f2bf_bits(w3[p * 512 + 256 + k]);   // w3[:, 256:512]
  } else {
    int t = idx - 163840;
    w4b[t] = f2bf_bits(w4[t]);
  }
}

// =====================================================================================
// K_b: conv1 (K=3, fp32 exact) + LayerNorm(128) + mask + relu -> h2 bf16 [131072 x 128]
// =====================================================================================
__global__ __launch_bounds__(256) void conv1_ln_kernel(
    const float* __restrict__ points, const int* __restrict__ mask,
    const float* __restrict__ w1, const float* __restrict__ g1,
    const float* __restrict__ be1, unsigned short* __restrict__ h2) {
  const int lane = threadIdx.x & 63;
  const int wv = threadIdx.x >> 6;
  const size_t p = (size_t)blockIdx.x * 4 + wv;
  const float x0 = points[p * 3 + 0];
  const float x1 = points[p * 3 + 1];
  const float x2 = points[p * 3 + 2];
  const int c0 = lane * 2, c1 = c0 + 1;
  float h00 = w1[c0 * 3] * x0 + w1[c0 * 3 + 1] * x1 + w1[c0 * 3 + 2] * x2;
  float h01 = w1[c1 * 3] * x0 + w1[c1 * 3 + 1] * x1 + w1[c1 * 3 + 2] * x2;
  float s = h00 + h01;
  for (int o = 32; o; o >>= 1) s += __shfl_xor(s, o);
  const float mu = s * (1.f / 128.f);
  const float d0 = h00 - mu, d1 = h01 - mu;
  float q = d0 * d0 + d1 * d1;
  for (int o = 32; o; o >>= 1) q += __shfl_xor(q, o);
  const float rs = rsqrtf(q * (1.f / 128.f) + LN_EPS);
  const bool vis = (mask[p] != 0);
  const float y0 = vis ? fmaxf(d0 * rs * g1[c0] + be1[c0], 0.f) : 0.f;
  const float y1 = vis ? fmaxf(d1 * rs * g1[c1] + be1[c1], 0.f) : 0.f;
  union { unsigned u; unsigned short s2[2]; } pk;
  pk.s2[0] = f2bf_bits(y0);
  pk.s2[1] = f2bf_bits(y1);
  ((unsigned*)h2)[p * 64 + lane] = pk.u;
}

// =====================================================================================
// MFMA GEMM: C[M,N] = A[M,K] * Bw[N,K]^T  (bf16 in, fp32 acc), 128x128 tile.
// 1D grid, swizzled into supertiles of (GROUP_ROWS row-tiles x NCT col-tiles),
// col-tile fastest, so concurrent blocks share A rows through L2/L3.
// EPI 0: out bf16 = acc + extra[col]                       (bias)
// EPI 1: out bf16 = acc + extra[(row>>12)*N + col]         (per-batch cvec)
// EPI 2: out fp32 pmax[rowTile*N + col] = colmax over 128 rows  (no store, no bias)
// EPI 3: EPI0 store + colmax(acc+bias) -> outp2[rowTile*N + col]
// =====================================================================================
template <int EPI, int NCT>
__global__ __launch_bounds__(256) void gemm_bt(
    const unsigned short* __restrict__ A, const unsigned short* __restrict__ Bw,
    void* __restrict__ outp, float* __restrict__ outp2,
    const float* __restrict__ extra, int M, int N, int K) {
  __shared__ __align__(16) char smA[128 * 64];   // 128 rows x 32 bf16 (64B), unpadded
  __shared__ __align__(16) char smB[128 * 64];
  __shared__ float lmax[2][128];

  const int tid = threadIdx.x;
  const int lane = tid & 63;
  const int w = tid >> 6;          // wave 0..3
  const int wm = w >> 1, wn = w & 1;

  // swizzled tile coordinates
  const int GROUP_ROWS = 64;
  const int perGroup = GROUP_ROWS * NCT;
  const int gid = blockIdx.x;
  const int group = gid / perGroup;
  const int within = gid - group * perGroup;
  const int rowTile = group * GROUP_ROWS + (within / NCT);
  const int colTile = within % NCT;
  const size_t rowBase = (size_t)rowTile * 128;
  const int colBase = colTile * 128;

  floatx4 acc[4][4];
  const floatx4 zero = {0.f, 0.f, 0.f, 0.f};
#pragma unroll
  for (int i = 0; i < 4; ++i)
#pragma unroll
    for (int j = 0; j < 4; ++j) acc[i][j] = zero;

  // staging: wave w stages rows [w*32, w*32+32) of both tiles, 2 calls each
  const int rSub = lane >> 2;
  const int cb16 = (lane & 3) * 16;
  const size_t Kb = (size_t)K * 2;
  const char* gA = (const char*)A + (rowBase + (size_t)(w * 32 + rSub)) * Kb + cb16;
  const char* gB = (const char*)Bw + ((size_t)colBase + (size_t)(w * 32 + rSub)) * Kb + cb16;
  char* lA = smA + w * 2048;
  char* lB = smB + w * 2048;
  const size_t skip16 = 16 * Kb;

  // fragment addressing
  const int fm = lane & 15, fq = lane >> 4;
  const char* pa0 = smA + (wm * 64 + fm) * 64 + fq * 16;
  const char* pb0 = smB + (wn * 64 + fm) * 64 + fq * 16;

  for (int k0 = 0; k0 < K; k0 += 32) {
    async_cp16(gA, lA);
    async_cp16(gA + skip16, lA + 1024);
    async_cp16(gB, lB);
    async_cp16(gB + skip16, lB + 1024);
    gA += 64; gB += 64;
    __syncthreads();
    bf16x8 af[4], bg[4];
#pragma unroll
    for (int i = 0; i < 4; ++i) af[i] = *(const bf16x8*)(pa0 + i * 16 * 64);
#pragma unroll
    for (int j = 0; j < 4; ++j) bg[j] = *(const bf16x8*)(pb0 + j * 16 * 64);
#pragma unroll
    for (int i = 0; i < 4; ++i)
#pragma unroll
      for (int j = 0; j < 4; ++j)
        acc[i][j] = __builtin_amdgcn_mfma_f32_16x16x32_bf16(af[i], bg[j], acc[i][j], 0, 0, 0);
    __syncthreads();
  }

  float m4[4] = {-1e30f, -1e30f, -1e30f, -1e30f};

  if (EPI == 0 || EPI == 1 || EPI == 3) {
    unsigned short* O = (unsigned short*)outp;
#pragma unroll
    for (int j = 0; j < 4; ++j) {
      const int col = colBase + wn * 64 + j * 16 + fm;
      const float ex = (EPI == 1) ? extra[(rowBase >> 12) * (size_t)N + col] : extra[col];
#pragma unroll
      for (int i = 0; i < 4; ++i) {
        const size_t row0 = rowBase + wm * 64 + i * 16 + fq * 4;
#pragma unroll
        for (int r = 0; r < 4; ++r) {
          const float v = acc[i][j][r] + ex;
          if (EPI == 3) m4[j] = fmaxf(m4[j], v);
          O[(row0 + r) * (size_t)N + col] = f2bf_bits(v);
        }
      }
    }
  } else {  // EPI == 2: pure column-max
#pragma unroll
    for (int j = 0; j < 4; ++j) {
#pragma unroll
      for (int i = 0; i < 4; ++i)
#pragma unroll
        for (int r = 0; r < 4; ++r) m4[j] = fmaxf(m4[j], acc[i][j][r]);
    }
  }

  if (EPI == 2 || EPI == 3) {
#pragma unroll
    for (int j = 0; j < 4; ++j) {
      m4[j] = fmaxf(m4[j], __shfl_xor(m4[j], 16));
      m4[j] = fmaxf(m4[j], __shfl_xor(m4[j], 32));
    }
    const float sel = (fq == 0) ? m4[0] : (fq == 1) ? m4[1] : (fq == 2) ? m4[2] : m4[3];
    lmax[wm][wn * 64 + fq * 16 + fm] = sel;
    __syncthreads();
    if (tid < 128) {
      const float v = fmaxf(lmax[0][tid], lmax[1][tid]);
      outp2[(size_t)rowTile * N + colBase + tid] = v;
    }
  }
}

// =====================================================================================
// gmax reduce: pg [B,32,256] (per-128-row-block colmax from GEMM2 epi) -> gmax [B,256]
// =====================================================================================
__global__ __launch_bounds__(256) void gmax_red_kernel(
    const float* __restrict__ pg, float* __restrict__ gmax) {
  const int b = blockIdx.x, t = threadIdx.x;
  float m = -1e30f;
  for (int s = 0; s < 32; ++s) m = fmaxf(m, pg[((size_t)b * 32 + s) * 256 + t]);
  gmax[b * 256 + t] = m;
}

// =====================================================================================
// cvec[b][p] = sum_{c<256} w3[p][c] * gmax[b][c]   (fp32 exact, tiny)
// =====================================================================================
__global__ __launch_bounds__(64) void cvec_kernel(
    const float* __restrict__ w3, const float* __restrict__ gmax,
    float* __restrict__ cvec) {
  __shared__ float gm[256];
  const int b = blockIdx.x, t = threadIdx.x;
  const int p = blockIdx.y * 64 + t;
  for (int i = 0; i < 4; ++i) gm[t * 4 + i] = gmax[b * 256 + t * 4 + i];
  __syncthreads();
  const float* wr = w3 + (size_t)p * 512;
  float s = 0.f;
  for (int c = 0; c < 256; ++c) s += wr[c] * gm[c];
  cvec[b * 512 + p] = s;
}

// =====================================================================================
// K_h: LayerNorm(512) + mask + relu, in place on h46 bf16 [131072 x 512]
// =====================================================================================
__global__ __launch_bounds__(256) void ln2_kernel(
    unsigned short* __restrict__ h46, const int* __restrict__ mask,
    const float* __restrict__ g2, const float* __restrict__ be2) {
  const int lane = threadIdx.x & 63;
  const int wv = threadIdx.x >> 6;
  const size_t p = (size_t)blockIdx.x * 4 + wv;
  unsigned short* row = h46 + p * 512;
  const int c0 = lane * 8;
  union { uint4 v; unsigned short s[8]; } in;
  in.v = *(const uint4*)(row + c0);
  float f[8];
  float s = 0.f;
#pragma unroll
  for (int k = 0; k < 8; ++k) { f[k] = bf2f(in.s[k]); s += f[k]; }
  for (int o = 32; o; o >>= 1) s += __shfl_xor(s, o);
  const float mu = s * (1.f / 512.f);
  float q = 0.f;
#pragma unroll
  for (int k = 0; k < 8; ++k) { const float d = f[k] - mu; q += d * d; }
  for (int o = 32; o; o >>= 1) q += __shfl_xor(q, o);
  const float rs = rsqrtf(q * (1.f / 512.f) + LN_EPS);
  const bool vis = (mask[p] != 0);
  union { uint4 v; unsigned short s[8]; } outv;
#pragma unroll
  for (int k = 0; k < 8; ++k) {
    const float y = vis ? fmaxf((f[k] - mu) * rs * g2[c0 + k] + be2[c0 + k], 0.f) : 0.f;
    outv.s[k] = f2bf_bits(y);
  }
  *(uint4*)(row + c0) = outv.v;
}

// =====================================================================================
// K_j: out[b][f] = max over 32 row-blocks of pmax + b4[f]
// =====================================================================================
__global__ __launch_bounds__(256) void final_kernel(
    const float* __restrict__ pmax, const float* __restrict__ b4,
    float* __restrict__ out) {
  const int idx = blockIdx.x * 256 + threadIdx.x;
  const int b = idx >> 10, f = idx & 1023;
  float m = -1e30f;
  for (int r = 0; r < 32; ++r) m = fmaxf(m, pmax[((size_t)(b * 32 + r)) * 1024 + f]);
  out[idx] = m + b4[f];
}

// =====================================================================================
extern "C" void kernel_launch(void* const* d_in, const int* in_sizes, int n_in,
                              void* d_out, int out_size, void* d_ws, size_t ws_size,
                              hipStream_t stream) {
  const float* points = (const float*)d_in[0];
  const int* mask = (const int*)d_in[1];
  const float* w1 = (const float*)d_in[2];
  const float* g1 = (const float*)d_in[3];
  const float* be1 = (const float*)d_in[4];
  const float* w2 = (const float*)d_in[5];
  const float* b2 = (const float*)d_in[6];
  const float* w3 = (const float*)d_in[7];
  const float* g2 = (const float*)d_in[8];
  const float* be2 = (const float*)d_in[9];
  const float* w4 = (const float*)d_in[10];
  const float* b4 = (const float*)d_in[11];
  float* out = (float*)d_out;
  char* ws = (char*)d_ws;

  // workspace layout (h46 aliases h2: h2 is dead before GEMM3 writes h46)
  const size_t OFF_H46 = 0;                         // 134217728 B (bf16 131072x512)
  const size_t OFF_H2 = 0;                          //  33554432 B (bf16 131072x128)
  const size_t OFF_H3 = 134217728;                  //  67108864 B (bf16 131072x256)
  const size_t OFF_W2B = OFF_H3 + 67108864;         //     65536 B
  const size_t OFF_W3RB = OFF_W2B + 65536;          //    262144 B
  const size_t OFF_W4B = OFF_W3RB + 262144;         //   1048576 B
  const size_t OFF_PG = OFF_W4B + 1048576;          //   1048576 B (pg: 1024x256 f32)
  const size_t OFF_GMAX = OFF_PG + 1048576;         //     32768 B
  const size_t OFF_CVEC = OFF_GMAX + 32768;         //     65536 B
  const size_t OFF_PMAX = OFF_CVEC + 65536;         //   4194304 B

  unsigned short* h2 = (unsigned short*)(ws + OFF_H2);
  unsigned short* h3 = (unsigned short*)(ws + OFF_H3);
  unsigned short* h46 = (unsigned short*)(ws + OFF_H46);
  unsigned short* w2b = (unsigned short*)(ws + OFF_W2B);
  unsigned short* w3Rb = (unsigned short*)(ws + OFF_W3RB);
  unsigned short* w4b = (unsigned short*)(ws + OFF_W4B);
  float* pg = (float*)(ws + OFF_PG);
  float* gmaxp = (float*)(ws + OFF_GMAX);
  float* cvecp = (float*)(ws + OFF_CVEC);
  float* pmaxp = (float*)(ws + OFF_PMAX);

  // 1. weights fp32->bf16
  wconv_kernel<<<2688, 256, 0, stream>>>(w2, w3, w4, w2b, w3Rb, w4b);
  // 2. conv1 + LN1 + mask + relu -> h2
  conv1_ln_kernel<<<32768, 256, 0, stream>>>(points, mask, w1, g1, be1, h2);
  // 3. h3 = h2 @ w2^T + b2, fused per-row-block colmax -> pg
  gemm_bt<3, 2><<<2048, 256, 0, stream>>>(h2, w2b, (void*)h3, pg, b2, 131072, 256, 128);
  // 4. gmax = max over row-blocks of pg
  gmax_red_kernel<<<32, 256, 0, stream>>>(pg, gmaxp);
  // 5. cvec = w3[:, :256] @ gmax
  cvec_kernel<<<dim3(32, 8), 64, 0, stream>>>(w3, gmaxp, cvecp);
  // 6. h4 = h3 @ w3[:,256:]^T + cvec[b]
  gemm_bt<1, 4><<<4096, 256, 0, stream>>>(h3, w3Rb, (void*)h46, nullptr, cvecp, 131072, 512, 256);
  // 7. LN2 + mask + relu in place
  ln2_kernel<<<32768, 256, 0, stream>>>(h46, mask, g2, be2);
  // 8. h7 colmax: fused per-row-block column-max -> pmax (bias deferred)
  gemm_bt<2, 8><<<8192, 256, 0, stream>>>(h46, w4b, nullptr, pmaxp, nullptr, 131072, 1024, 512);
  // 9. out = max over row-blocks + b4
  final_kernel<<<128, 256, 0, stream>>>(pmaxp, b4, out);
}